// Round 7
// baseline (236.212 us; speedup 1.0000x reference)
//
#include <hip/hip_runtime.h>
#include <cstdint>

typedef __attribute__((ext_vector_type(8))) short short8;
typedef __attribute__((ext_vector_type(4))) float floatx4;

__device__ __forceinline__ unsigned short f2bf(float f) {
  uint32_t u = __builtin_bit_cast(uint32_t, f);
  u += 0x7fffu + ((u >> 16) & 1u);   // RNE
  return (unsigned short)(u >> 16);
}
// pack bf16(lo)|bf16(hi)<<16, round-half-up: 2 adds + 1 v_perm
__device__ __forceinline__ uint32_t pkbf(float lo, float hi) {
  uint32_t a = __builtin_bit_cast(uint32_t, lo) + 0x8000u;
  uint32_t b = __builtin_bit_cast(uint32_t, hi) + 0x8000u;
  return __builtin_amdgcn_perm(b, a, 0x07060302);
}
// async global->LDS, 16B per lane (HW: wave-uniform LDS base + lane*16;
// GLOBAL source address is per-lane -> swizzle lives in the source)
__device__ __forceinline__ void gll16(const void* g, void* l) {
  __builtin_amdgcn_global_load_lds(
      (const __attribute__((address_space(1))) unsigned int*)g,
      (__attribute__((address_space(3))) unsigned int*)l, 16, 0, 0);
}

// ---------------- kernel 1a: build Wt LDS-image (fp32 -> bf16, swizzled) -------
// [bz(3)][kb(24)][row(192)][cs(4)] 16B chunks; chunk cs holds data k-chunk
// c = cs ^ ((row>>1)&3)  (XOR bank swizzle baked into the image).
__global__ void prep_w_kernel(const float* __restrict__ Wq,
                              const float* __restrict__ Wk,
                              const float* __restrict__ Wv,
                              unsigned short* __restrict__ Wt) {
  int id = blockIdx.x * 256 + threadIdx.x;      // 55296 chunks total
  int bz = id / 18432, rem = id - bz * 18432;
  int kb = rem / 768, s = rem - kb * 768;
  int row = s >> 2, cs = s & 3;                  // row = output col nn 0..191
  int c = cs ^ ((row >> 1) & 3);
  const float* W = (bz == 0) ? Wq : (bz == 1) ? Wk : Wv;
  int k0 = kb * 32 + c * 8;
  unsigned short v[8];
#pragma unroll
  for (int e = 0; e < 8; ++e) v[e] = f2bf(W[(size_t)(k0 + e) * 192 + row]);
  uint4 o;
  o.x = v[0] | ((uint32_t)v[1] << 16);
  o.y = v[2] | ((uint32_t)v[3] << 16);
  o.z = v[4] | ((uint32_t)v[5] << 16);
  o.w = v[6] | ((uint32_t)v[7] << 16);
  *(uint4*)(Wt + (size_t)id * 8) = o;
}

// ---------------- kernel 1b: x fp32 -> bf16, row-major (pure stream) ----------
__global__ void prep_x_kernel(const float* __restrict__ x,
                              unsigned short* __restrict__ xb) {
  size_t id = (size_t)blockIdx.x * 256 + threadIdx.x;  // 3,145,728 16B chunks
  float4 f0 = *(const float4*)(x + id * 8);
  float4 f1 = *(const float4*)(x + id * 8 + 4);
  uint4 o;
  o.x = pkbf(f0.x, f0.y);
  o.y = pkbf(f0.z, f0.w);
  o.z = pkbf(f1.x, f1.y);
  o.w = pkbf(f1.z, f1.w);
  *(uint4*)(xb + id * 8) = o;
}

// ======== proj epilogue (shared by both proj variants) ========
#define PROJ_EPILOGUE                                                          \
  const float R_LG = 0.8304820237218406f; /* log2(10000)/16 */                 \
  if (bz < 2) {                                                                \
    unsigned short* dst = (bz == 0) ? q_ws : k_ws;                             \
    if (wc == 0) {                                                             \
      _Pragma("unroll") for (int mi = 0; mi < 2; ++mi)                         \
      _Pragma("unroll") for (int r = 0; r < 4; ++r) {                          \
        int row_g = m0 + wr * 32 + mi * 16 + quad * 4 + r;                     \
        int t_pos = row_g & 511;                                               \
        float v0 = acc[mi][0][r], v1 = acc[mi][1][r];                          \
        {                                                                      \
          float i0 = (float)(ln >> 1);                                         \
          float f0 = exp2f(-i0 * R_LG);                                        \
          float f1 = exp2f(-(i0 + 8.0f) * R_LG);                               \
          float s0, c0, s1, c1;                                                \
          sincosf((float)t_pos * f0, &s0, &c0);                                \
          sincosf((float)t_pos * f1, &s1, &c1);                                \
          float p0 = __shfl_xor(v0, 1), p1 = __shfl_xor(v1, 1);                \
          v0 = (ln & 1) ? (v0 * c0 + p0 * s0) : (v0 * c0 - p0 * s0);           \
          v1 = (ln & 1) ? (v1 * c1 + p1 * s1) : (v1 * c1 - p1 * s1);           \
        }                                                                      \
        dst[(size_t)row_g * 192 + ln] = f2bf(v0);                              \
        dst[(size_t)row_g * 192 + 16 + ln] = f2bf(v1);                         \
        _Pragma("unroll") for (int nj = 2; nj < 6; ++nj)                       \
            dst[(size_t)row_g * 192 + nj * 16 + ln] = f2bf(acc[mi][nj][r]);    \
      }                                                                        \
    } else {                                                                   \
      _Pragma("unroll") for (int mi = 0; mi < 2; ++mi)                         \
      _Pragma("unroll") for (int r = 0; r < 4; ++r) {                          \
        int row_g = m0 + wr * 32 + mi * 16 + quad * 4 + r;                     \
        _Pragma("unroll") for (int nj = 0; nj < 6; ++nj)                       \
            dst[(size_t)row_g * 192 + 96 + nj * 16 + ln] =                     \
                f2bf(acc[mi][nj][r]);                                          \
      }                                                                        \
    }                                                                          \
  } else {                                                                     \
    const int dbase = wc * 96;                                                 \
    _Pragma("unroll") for (int mi = 0; mi < 2; ++mi) {                         \
      int rb = m0 + wr * 32 + mi * 16 + quad * 4;                              \
      int bb = rb >> 9, t = rb & 511;                                          \
      _Pragma("unroll") for (int nj = 0; nj < 6; ++nj) {                       \
        ushort4 pv;                                                            \
        pv.x = f2bf(acc[mi][nj][0]);                                           \
        pv.y = f2bf(acc[mi][nj][1]);                                           \
        pv.z = f2bf(acc[mi][nj][2]);                                           \
        pv.w = f2bf(acc[mi][nj][3]);                                           \
        *(ushort4*)&v_ws[((size_t)bb * 192 + dbase + nj * 16 + ln) * 512 + t] = pv; \
      }                                                                        \
    }                                                                          \
  }

// ---------------- kernel 2A: proj, pure-DMA variant (m97-clone) ----------------
// Both A (bf16 x, source-swizzled per-lane addrs) and B (Wt image) stream via
// global_load_lds. 3-buffer, counted vmcnt(4) (wait = DMA issued 1 iter ago),
// zero staging VGPR/VALU. LDS 48KB -> 3 blocks/CU.
__global__ __launch_bounds__(256, 3) void proj_dma_kernel(
    const unsigned short* __restrict__ xb, const unsigned short* __restrict__ Wt,
    unsigned short* __restrict__ q_ws, unsigned short* __restrict__ k_ws,
    unsigned short* __restrict__ v_ws) {
  __shared__ __align__(16) unsigned short A_lds[3][64 * 32];    // 3 x 4KB
  __shared__ __align__(16) unsigned short B_lds[3][192 * 32];   // 3 x 12KB
  const int tid = threadIdx.x;
  const int w = tid >> 6, l = tid & 63, quad = l >> 4, ln = l & 15;
  const int wr = w & 1, wc = w >> 1;
  const int m0 = blockIdx.x * 64;
  const int bz = blockIdx.y;

  // A source: lane owns 16B chunk; swizzle in the GLOBAL address (LDS linear)
  const int arow = tid >> 2, ac = tid & 3;
  const int aswz = ac ^ ((arow >> 1) & 3);
  const unsigned short* xsrc = xb + (size_t)(m0 + arow) * 768 + aswz * 8;
  const unsigned short* wimg = Wt + (size_t)bz * 18432 * 8;

  const int fq = ((quad ^ ((ln >> 1) & 3)) << 4);

  floatx4 acc[2][6];
#pragma unroll
  for (int mi = 0; mi < 2; ++mi)
#pragma unroll
    for (int nj = 0; nj < 6; ++nj) acc[mi][nj] = floatx4{0.f, 0.f, 0.f, 0.f};

#define DMAA(KB, BB) gll16(xsrc + (KB) * 32, (char*)&A_lds[BB][0] + tid * 16)
#define DMAB(KB, BB)                                                  \
  do {                                                                \
    const unsigned short* src = wimg + (size_t)(KB)*6144;             \
    char* dstb = (char*)&B_lds[BB][0];                                \
    gll16(src + tid * 8, dstb + tid * 16);                            \
    gll16(src + (256 + tid) * 8, dstb + (256 + tid) * 16);            \
    gll16(src + (512 + tid) * 8, dstb + (512 + tid) * 16);            \
  } while (0)
#define WAITBAR4 \
  asm volatile("s_waitcnt vmcnt(4) lgkmcnt(0)\n\ts_barrier" ::: "memory")
#define WAITBAR0 \
  asm volatile("s_waitcnt vmcnt(0) lgkmcnt(0)\n\ts_barrier" ::: "memory")
#define PCOMPUTE(C)                                                              \
  do {                                                                           \
    short8 af0 = *(const short8*)((const char*)&A_lds[C][0] +                    \
                                  (wr * 32 + ln) * 64 + fq);                     \
    short8 af1 = *(const short8*)((const char*)&A_lds[C][0] +                    \
                                  (wr * 32 + 16 + ln) * 64 + fq);                \
    _Pragma("unroll") for (int nj = 0; nj < 6; ++nj) {                           \
      short8 bf = *(const short8*)((const char*)&B_lds[C][0] +                   \
                                   (wc * 96 + nj * 16 + ln) * 64 + fq);          \
      acc[0][nj] = __builtin_amdgcn_mfma_f32_16x16x32_bf16(af0, bf, acc[0][nj],  \
                                                           0, 0, 0);             \
      acc[1][nj] = __builtin_amdgcn_mfma_f32_16x16x32_bf16(af1, bf, acc[1][nj],  \
                                                           0, 0, 0);             \
    }                                                                            \
  } while (0)
// BODY(J): issue DMA(J+1) into buf (J+1)%3; wait DMA(J) (4 newest outstanding
// are this iter's) -> vmcnt(4); compute buf J%3. Reuse 3 iters apart: safe.
#define BODY(J, C, N)                                   \
  do {                                                  \
    DMAA((J) + 1, N);                                   \
    DMAB((J) + 1, N);                                   \
    WAITBAR4;                                           \
    PCOMPUTE(C);                                        \
  } while (0)

  DMAA(0, 0);
  DMAB(0, 0);
  BODY(0, 0, 1);
  for (int t = 1; t <= 19; t += 3) {  // j = 1..21
    BODY(t, 1, 2);
    BODY(t + 1, 2, 0);
    BODY(t + 2, 0, 1);
  }
  BODY(22, 1, 2);          // issues DMA(23)
  { WAITBAR0; PCOMPUTE(2); }  // j=23
#undef DMAA
#undef DMAB
#undef WAITBAR4
#undef WAITBAR0
#undef PCOMPUTE
#undef BODY

  PROJ_EPILOGUE
}

// ---------------- kernel 2B: proj v5 (fallback if workspace too small) --------
__global__ __launch_bounds__(256, 3) void proj_kernel(
    const float* __restrict__ x, const unsigned short* __restrict__ Wt,
    unsigned short* __restrict__ q_ws, unsigned short* __restrict__ k_ws,
    unsigned short* __restrict__ v_ws) {
  __shared__ __align__(16) unsigned short A_lds[3][64 * 32];    // 3 x 4KB
  __shared__ __align__(16) unsigned short B_lds[3][192 * 32];   // 3 x 12KB
  const int tid = threadIdx.x;
  const int w = tid >> 6, l = tid & 63, quad = l >> 4, ln = l & 15;
  const int wr = w & 1, wc = w >> 1;
  const int m0 = blockIdx.x * 64;
  const int bz = blockIdx.y;

  const int arow = tid >> 2, ac = tid & 3;
  const int aslot = ((ac ^ ((arow >> 1) & 3)) << 4);
  const float* xp = x + (size_t)(m0 + arow) * 768 + ac * 8;
  const unsigned short* wimg = Wt + (size_t)bz * 18432 * 8;
  const int fq = ((quad ^ ((ln >> 1) & 3)) << 4);

  floatx4 acc[2][6];
#pragma unroll
  for (int mi = 0; mi < 2; ++mi)
#pragma unroll
    for (int nj = 0; nj < 6; ++nj) acc[mi][nj] = floatx4{0.f, 0.f, 0.f, 0.f};

  float4 ax0, ay0, ax1, ay1, ax2, ay2;

#define LOADA(S, K0)                               \
  do {                                             \
    ax##S = *(const float4*)(xp + (K0));           \
    ay##S = *(const float4*)(xp + (K0) + 4);       \
  } while (0)
#define STAGEA(S, AB)                                             \
  do {                                                            \
    uint4 ap;                                                     \
    ap.x = pkbf(ax##S.x, ax##S.y);                                \
    ap.y = pkbf(ax##S.z, ax##S.w);                                \
    ap.z = pkbf(ay##S.x, ay##S.y);                                \
    ap.w = pkbf(ay##S.z, ay##S.w);                                \
    *(uint4*)((char*)&A_lds[AB][0] + arow * 64 + aslot) = ap;     \
  } while (0)
#define DMAB(KB1, BB)                                             \
  do {                                                            \
    const unsigned short* src = wimg + (size_t)(KB1)*6144;        \
    char* dstb = (char*)&B_lds[BB][0];                            \
    gll16(src + tid * 8, dstb + tid * 16);                        \
    gll16(src + (256 + tid) * 8, dstb + (256 + tid) * 16);        \
    gll16(src + (512 + tid) * 8, dstb + (512 + tid) * 16);        \
  } while (0)
#define WAITBAR(N)                                                          \
  asm volatile("s_waitcnt vmcnt(" #N ") lgkmcnt(0)\n\ts_barrier" ::: "memory")
#define PCOMPUTE(C)                                                              \
  do {                                                                           \
    short8 af0 = *(const short8*)((const char*)&A_lds[C][0] +                    \
                                  (wr * 32 + ln) * 64 + fq);                     \
    short8 af1 = *(const short8*)((const char*)&A_lds[C][0] +                    \
                                  (wr * 32 + 16 + ln) * 64 + fq);                \
    _Pragma("unroll") for (int nj = 0; nj < 6; ++nj) {                           \
      short8 bf = *(const short8*)((const char*)&B_lds[C][0] +                   \
                                   (wc * 96 + nj * 16 + ln) * 64 + fq);          \
      acc[0][nj] = __builtin_amdgcn_mfma_f32_16x16x32_bf16(af0, bf, acc[0][nj],  \
                                                           0, 0, 0);             \
      acc[1][nj] = __builtin_amdgcn_mfma_f32_16x16x32_bf16(af1, bf, acc[1][nj],  \
                                                           0, 0, 0);             \
    }                                                                            \
  } while (0)
#define BODY(KB, C, P)            \
  do {                            \
    STAGEA(P, P);                 \
    DMAB((KB) + 1, P);            \
    LOADA(C, ((KB) + 3) * 32);    \
    WAITBAR(7);                   \
    PCOMPUTE(C);                  \
  } while (0)

  DMAB(0, 0);
  LOADA(0, 0);
  LOADA(1, 32);
  LOADA(2, 64);
  STAGEA(0, 0);

  BODY(0, 0, 1);
  for (int t = 1; t <= 16; t += 3) {
    BODY(t, 1, 2);
    BODY(t + 1, 2, 0);
    BODY(t + 2, 0, 1);
  }
  BODY(19, 1, 2);
  BODY(20, 2, 0);
  { STAGEA(1, 1); DMAB(22, 1); WAITBAR(5); PCOMPUTE(0); }
  { STAGEA(2, 2); DMAB(23, 2); WAITBAR(3); PCOMPUTE(1); }
  { WAITBAR(0); PCOMPUTE(2); }
#undef LOADA
#undef STAGEA
#undef DMAB
#undef WAITBAR
#undef PCOMPUTE
#undef BODY

  PROJ_EPILOGUE
}

// ---------------- kernel 3: causal flash attention (MFMA, KVBLK=32) -----------
// v6: KVBLK 64->32 => LDS 62.4KB -> 33.3KB -> 2 blocks/CU: the per-kt barrier
// drains finally get cross-block hiding (m114). Inner structure unchanged.
__global__ __launch_bounds__(256) void attn_kernel(
    const unsigned short* __restrict__ q_ws, const unsigned short* __restrict__ k_ws,
    const unsigned short* __restrict__ v_ws, float* __restrict__ out) {
  __shared__ __align__(16) unsigned short K_lds[32 * 200];
  __shared__ __align__(16) unsigned short V_lds[192 * 40];   // V^T: [dim][key]
  __shared__ __align__(16) unsigned short P_lds[4][16 * 40]; // per-wave P
  const int tid = threadIdx.x;
  const int w = tid >> 6, l = tid & 63, quad = l >> 4, ln = l & 15;
  const int b = blockIdx.y;
  const int qt = (blockIdx.y < 32) ? blockIdx.x : 7 - blockIdx.x;
  const int q0 = qt * 64;

  // preload Q A-fragments
  short8 qf[6];
  {
    const unsigned short* qp =
        q_ws + (size_t)(b * 512 + q0 + w * 16 + ln) * 192 + quad * 8;
#pragma unroll
    for (int kk = 0; kk < 6; ++kk) qf[kk] = *(const short8*)(qp + kk * 32);
  }

  float m_i[4], l_i[4];
  floatx4 o[12];
#pragma unroll
  for (int r = 0; r < 4; ++r) { m_i[r] = -1e30f; l_i[r] = 0.f; }
#pragma unroll
  for (int nt = 0; nt < 12; ++nt) o[nt] = floatx4{0.f, 0.f, 0.f, 0.f};
  const float sm_scale = 0.07216878364870323f;  // 192^-0.5

  const int ktmax = 2 * qt + 1;
  for (int kt = 0; kt <= ktmax; ++kt) {
    const int k0 = kt * 32;
    __syncthreads();  // previous iteration's LDS reads done before overwrite
    // stage K tile [32][192]: 768 16B chunks
#pragma unroll
    for (int it = 0; it < 3; ++it) {
      int idx = it * 256 + tid;
      int row = idx / 24, c = idx - row * 24;
      uint4 v = *(const uint4*)(k_ws + (size_t)(b * 512 + k0 + row) * 192 + c * 8);
      *(uint4*)&K_lds[row * 200 + c * 8] = v;
    }
    // stage V^T tile [192][32]: 768 chunks
#pragma unroll
    for (int it = 0; it < 3; ++it) {
      int idx = it * 256 + tid;
      int row = idx >> 2, c = idx & 3;
      uint4 v = *(const uint4*)(v_ws + (size_t)(b * 192 + row) * 512 + k0 + c * 8);
      *(uint4*)&V_lds[row * 40 + c * 8] = v;
    }
    __syncthreads();

    // S = Q K^T (scaled)
    float s[2][4];
    __builtin_amdgcn_s_setprio(1);
#pragma unroll
    for (int nt = 0; nt < 2; ++nt) {
      floatx4 sa = floatx4{0.f, 0.f, 0.f, 0.f};
#pragma unroll
      for (int kk = 0; kk < 6; ++kk) {
        short8 kf = *(const short8*)&K_lds[(nt * 16 + ln) * 200 + kk * 32 + quad * 8];
        sa = __builtin_amdgcn_mfma_f32_16x16x32_bf16(qf[kk], kf, sa, 0, 0, 0);
      }
#pragma unroll
      for (int r = 0; r < 4; ++r) s[nt][r] = sa[r] * sm_scale;
    }
    __builtin_amdgcn_s_setprio(0);
    if (kt >= 2 * qt) {  // diagonal-region tiles
      int kd = (kt - 2 * qt) * 32;
#pragma unroll
      for (int nt = 0; nt < 2; ++nt)
#pragma unroll
        for (int r = 0; r < 4; ++r)
          if (kd + nt * 16 + ln > w * 16 + quad * 4 + r) s[nt][r] = -1e30f;
    }
    // online softmax (row = quad*4+r)
    float alpha[4];
#pragma unroll
    for (int r = 0; r < 4; ++r) {
      float mx = fmaxf(s[0][r], s[1][r]);
      mx = fmaxf(mx, __shfl_xor(mx, 1));
      mx = fmaxf(mx, __shfl_xor(mx, 2));
      mx = fmaxf(mx, __shfl_xor(mx, 4));
      mx = fmaxf(mx, __shfl_xor(mx, 8));
      float mnew = fmaxf(m_i[r], mx);
      alpha[r] = __expf(m_i[r] - mnew);
      float sum = 0.f;
#pragma unroll
      for (int nt = 0; nt < 2; ++nt) {
        s[nt][r] = __expf(s[nt][r] - mnew);
        sum += s[nt][r];
      }
      sum += __shfl_xor(sum, 1);
      sum += __shfl_xor(sum, 2);
      sum += __shfl_xor(sum, 4);
      sum += __shfl_xor(sum, 8);
      l_i[r] = l_i[r] * alpha[r] + sum;
      m_i[r] = mnew;
    }
#pragma unroll
    for (int nt = 0; nt < 12; ++nt)
#pragma unroll
      for (int r = 0; r < 4; ++r) o[nt][r] *= alpha[r];

    // P: C/D layout -> A layout via per-wave LDS
#pragma unroll
    for (int nt = 0; nt < 2; ++nt)
#pragma unroll
      for (int r = 0; r < 4; ++r)
        P_lds[w][(quad * 4 + r) * 40 + nt * 16 + ln] = f2bf(s[nt][r]);
    __asm__ volatile("s_waitcnt lgkmcnt(0)" ::: "memory");  // wave-local write->read

    // O += P V (single k-slab: KVBLK=32)
    __builtin_amdgcn_s_setprio(1);
    {
      short8 pf = *(const short8*)&P_lds[w][ln * 40 + quad * 8];
#pragma unroll
      for (int nt = 0; nt < 12; ++nt) {
        short8 vf = *(const short8*)&V_lds[(nt * 16 + ln) * 40 + quad * 8];
        o[nt] = __builtin_amdgcn_mfma_f32_16x16x32_bf16(pf, vf, o[nt], 0, 0, 0);
      }
    }
    __builtin_amdgcn_s_setprio(0);
  }

  // epilogue: O/l -> fp32 out [b][t][dim]
#pragma unroll
  for (int r = 0; r < 4; ++r) {
    float inv = 1.0f / l_i[r];
    size_t rowoff = (size_t)(b * 512 + q0 + w * 16 + quad * 4 + r) * 192;
#pragma unroll
    for (int nt = 0; nt < 12; ++nt)
      out[rowoff + nt * 16 + ln] = o[nt][r] * inv;
  }
}

extern "C" void kernel_launch(void* const* d_in, const int* in_sizes, int n_in,
                              void* d_out, int out_size, void* d_ws, size_t ws_size,
                              hipStream_t stream) {
  const float* x = (const float*)d_in[0];
  const float* Wq = (const float*)d_in[1];
  const float* Wk = (const float*)d_in[2];
  const float* Wv = (const float*)d_in[3];
  float* out = (float*)d_out;

  char* ws = (char*)d_ws;
  const size_t QKV_BYTES = (size_t)64 * 512 * 192 * 2;  // 12,582,912
  const size_t WT_BYTES = (size_t)55296 * 16;           // 884,736
  const size_t XBF_BYTES = (size_t)32768 * 768 * 2;     // 50,331,648
  unsigned short* q_ws = (unsigned short*)(ws);
  unsigned short* k_ws = (unsigned short*)(ws + QKV_BYTES);
  unsigned short* v_ws = (unsigned short*)(ws + 2 * QKV_BYTES);
  unsigned short* Wt = (unsigned short*)(ws + 3 * QKV_BYTES);
  unsigned short* xb = (unsigned short*)(ws + 3 * QKV_BYTES + WT_BYTES);

  const bool big = ws_size >= 3 * QKV_BYTES + WT_BYTES + XBF_BYTES;

  hipLaunchKernelGGL(prep_w_kernel, dim3(216), dim3(256), 0, stream, Wq, Wk, Wv, Wt);
  if (big) {
    hipLaunchKernelGGL(prep_x_kernel, dim3(12288), dim3(256), 0, stream, x, xb);
    hipLaunchKernelGGL(proj_dma_kernel, dim3(512, 3), dim3(256), 0, stream, xb, Wt,
                       q_ws, k_ws, v_ws);
  } else {
    hipLaunchKernelGGL(proj_kernel, dim3(512, 3), dim3(256), 0, stream, x, Wt,
                       q_ws, k_ws, v_ws);
  }
  hipLaunchKernelGGL(attn_kernel, dim3(8, 64), dim3(256), 0, stream, q_ws, k_ws, v_ws, out);
}

// Round 8
// 234.581 us; speedup vs baseline: 1.0070x; 1.0070x over previous
//
#include <hip/hip_runtime.h>
#include <cstdint>

typedef __attribute__((ext_vector_type(8))) short short8;
typedef __attribute__((ext_vector_type(4))) float floatx4;

__device__ __forceinline__ unsigned short f2bf(float f) {
  uint32_t u = __builtin_bit_cast(uint32_t, f);
  u += 0x7fffu + ((u >> 16) & 1u);   // RNE
  return (unsigned short)(u >> 16);
}
// pack bf16(lo)|bf16(hi)<<16, round-half-up: 2 adds + 1 v_perm
__device__ __forceinline__ uint32_t pkbf(float lo, float hi) {
  uint32_t a = __builtin_bit_cast(uint32_t, lo) + 0x8000u;
  uint32_t b = __builtin_bit_cast(uint32_t, hi) + 0x8000u;
  return __builtin_amdgcn_perm(b, a, 0x07060302);
}
// async global->LDS, 16B per lane (HW: wave-uniform LDS base + lane*16)
__device__ __forceinline__ void gll16(const void* g, void* l) {
  __builtin_amdgcn_global_load_lds(
      (const __attribute__((address_space(1))) unsigned int*)g,
      (__attribute__((address_space(3))) unsigned int*)l, 16, 0, 0);
}

// ---------------- kernel 1: build Wt LDS-image (fp32 -> bf16, swizzled) --------
// [bz(3)][kb(24)][row(192)][cs(4)] 16B chunks; chunk cs holds data k-chunk
// c = cs ^ ((row>>1)&3)  (XOR bank swizzle baked into the image).
__global__ void prep_w_kernel(const float* __restrict__ Wq,
                              const float* __restrict__ Wk,
                              const float* __restrict__ Wv,
                              unsigned short* __restrict__ Wt) {
  int id = blockIdx.x * 256 + threadIdx.x;      // 55296 chunks total
  int bz = id / 18432, rem = id - bz * 18432;
  int kb = rem / 768, s = rem - kb * 768;
  int row = s >> 2, cs = s & 3;                  // row = output col nn 0..191
  int c = cs ^ ((row >> 1) & 3);
  const float* W = (bz == 0) ? Wq : (bz == 1) ? Wk : Wv;
  int k0 = kb * 32 + c * 8;
  unsigned short v[8];
#pragma unroll
  for (int e = 0; e < 8; ++e) v[e] = f2bf(W[(size_t)(k0 + e) * 192 + row]);
  uint4 o;
  o.x = v[0] | ((uint32_t)v[1] << 16);
  o.y = v[2] | ((uint32_t)v[3] << 16);
  o.z = v[4] | ((uint32_t)v[5] << 16);
  o.w = v[6] | ((uint32_t)v[7] << 16);
  *(uint4*)(Wt + (size_t)id * 8) = o;
}

// ---------------- kernel 2: QKV projection + RoPE (v7) ----------------
// r7 post-mortem: DMA-A path's prep_x cost ate its gain; the real proj limit
// is compute-per-barrier (12 MFMA ~60cy vs ~370cy overhead -> 14% MfmaUtil).
// v7: 128-row blocks (grid 256x3); wave = 32 rows x 192 cols = 24 MFMA/iter
// (2x), per-CU barrier-iters halved. A reg-staged from fp32 x (v5 engine),
// B via global_load_lds from pre-swizzled Wt image. 3-buffer rotation,
// counted vmcnt: steady 7 = ops GUARANTEED younger than the waited DMA
// (this iter's 3 DMA + 4 A-loads; barrier asm blocks hoisting) -> safe under
// any compiler reordering of loads vs DMA. Tails 3/3/0.
// LDS 60KB -> 2 blocks/CU; ~170 VGPR under launch_bounds(256,2) cap 256.
__global__ __launch_bounds__(256, 2) void proj_kernel(
    const float* __restrict__ x, const unsigned short* __restrict__ Wt,
    unsigned short* __restrict__ q_ws, unsigned short* __restrict__ k_ws,
    unsigned short* __restrict__ v_ws) {
  __shared__ __align__(16) unsigned short A_lds[3][128 * 32];   // 3 x 8KB
  __shared__ __align__(16) unsigned short B_lds[3][192 * 32];   // 3 x 12KB
  const int tid = threadIdx.x;
  const int w = tid >> 6, l = tid & 63, quad = l >> 4, ln = l & 15;
  const int m0 = blockIdx.x * 128;
  const int bz = blockIdx.y;

  // A staging: thread owns chunks (row arow, ac) and (row arow+64, ac)
  const int arow = tid >> 2, ac = tid & 3;
  const int aslot = ((ac ^ ((arow >> 1) & 3)) << 4);  // same for arow+64
  const float* xp0 = x + (size_t)(m0 + arow) * 768 + ac * 8;
  const float* xp1 = xp0 + (size_t)64 * 768;
  const unsigned short* wimg = Wt + (size_t)bz * 18432 * 8;

  // fragment read chunk: (row>>1)&3 == (ln>>1)&3 (all frag row bases %8==0)
  const int fq = ((quad ^ ((ln >> 1) & 3)) << 4);

  floatx4 acc[2][12];
#pragma unroll
  for (int mi = 0; mi < 2; ++mi)
#pragma unroll
    for (int nj = 0; nj < 12; ++nj) acc[mi][nj] = floatx4{0.f, 0.f, 0.f, 0.f};

  // 3 rotating A-prefetch register sets, 2 rows each (4 float4)
  float4 a0p, a0q, a0r, a0s, a1p, a1q, a1r, a1s, a2p, a2q, a2r, a2s;

#define LOADA(S, K0)                               \
  do {                                             \
    a##S##p = *(const float4*)(xp0 + (K0));        \
    a##S##q = *(const float4*)(xp0 + (K0) + 4);    \
    a##S##r = *(const float4*)(xp1 + (K0));        \
    a##S##s = *(const float4*)(xp1 + (K0) + 4);    \
  } while (0)
#define STAGEA(S, AB)                                                   \
  do {                                                                  \
    uint4 ap;                                                           \
    ap.x = pkbf(a##S##p.x, a##S##p.y);                                  \
    ap.y = pkbf(a##S##p.z, a##S##p.w);                                  \
    ap.z = pkbf(a##S##q.x, a##S##q.y);                                  \
    ap.w = pkbf(a##S##q.z, a##S##q.w);                                  \
    *(uint4*)((char*)&A_lds[AB][0] + arow * 64 + aslot) = ap;           \
    ap.x = pkbf(a##S##r.x, a##S##r.y);                                  \
    ap.y = pkbf(a##S##r.z, a##S##r.w);                                  \
    ap.z = pkbf(a##S##s.x, a##S##s.y);                                  \
    ap.w = pkbf(a##S##s.z, a##S##s.w);                                  \
    *(uint4*)((char*)&A_lds[AB][0] + (arow + 64) * 64 + aslot) = ap;    \
  } while (0)
#define DMAB(KB1, BB)                                             \
  do {                                                            \
    const unsigned short* src = wimg + (size_t)(KB1)*6144;        \
    char* dstb = (char*)&B_lds[BB][0];                            \
    gll16(src + tid * 8, dstb + tid * 16);                        \
    gll16(src + (256 + tid) * 8, dstb + (256 + tid) * 16);        \
    gll16(src + (512 + tid) * 8, dstb + (512 + tid) * 16);        \
  } while (0)
#define WAITBAR(N)                                                          \
  asm volatile("s_waitcnt vmcnt(" #N ") lgkmcnt(0)\n\ts_barrier" ::: "memory")
#define PCOMPUTE(C)                                                              \
  do {                                                                           \
    short8 af0 = *(const short8*)((const char*)&A_lds[C][0] +                    \
                                  (w * 32 + ln) * 64 + fq);                      \
    short8 af1 = *(const short8*)((const char*)&A_lds[C][0] +                    \
                                  (w * 32 + 16 + ln) * 64 + fq);                 \
    _Pragma("unroll") for (int nj = 0; nj < 12; ++nj) {                          \
      short8 bf = *(const short8*)((const char*)&B_lds[C][0] +                   \
                                   (nj * 16 + ln) * 64 + fq);                    \
      acc[0][nj] = __builtin_amdgcn_mfma_f32_16x16x32_bf16(af0, bf, acc[0][nj],  \
                                                           0, 0, 0);             \
      acc[1][nj] = __builtin_amdgcn_mfma_f32_16x16x32_bf16(af1, bf, acc[1][nj],  \
                                                           0, 0, 0);             \
    }                                                                            \
  } while (0)
// BODY(KB): stage A set P=(KB+1)%3 into buf P; DMA B(KB+1) into buf P;
// reload set C=KB%3 with k-step KB+3; wait(7) guarantees DMAB(KB) drained
// (7 = this iter's 3 DMA + 4 loads, which cannot hoist above the barrier).
#define BODY(KB, C, P)            \
  do {                            \
    STAGEA(P, P);                 \
    DMAB((KB) + 1, P);            \
    LOADA(C, ((KB) + 3) * 32);    \
    WAITBAR(7);                   \
    PCOMPUTE(C);                  \
  } while (0)

  // prologue: DMA k0; A-loads k0,k1,k2; stage a[0]
  DMAB(0, 0);
  LOADA(0, 0);
  LOADA(1, 32);
  LOADA(2, 64);
  STAGEA(0, 0);

  BODY(0, 0, 1);
  for (int t = 1; t <= 16; t += 3) {  // iters 1..18
    BODY(t, 1, 2);
    BODY(t + 1, 2, 0);
    BODY(t + 2, 0, 1);
  }
  BODY(19, 1, 2);
  BODY(20, 2, 0);
  { STAGEA(1, 1); DMAB(22, 1); WAITBAR(3); PCOMPUTE(0); }  // 21
  { STAGEA(2, 2); DMAB(23, 2); WAITBAR(3); PCOMPUTE(1); }  // 22
  { WAITBAR(0); PCOMPUTE(2); }                             // 23
#undef LOADA
#undef STAGEA
#undef DMAB
#undef WAITBAR
#undef PCOMPUTE
#undef BODY

  // epilogue. wave w: rows m0 + w*32 + mi*16 + quad*4 + r; cols nj*16+ln.
  // bz 0: Q (RoPE nj0,1) | bz 1: K (RoPE nj0,1) | bz 2: V transposed [b][dim][t]
  const float R_LG = 0.8304820237218406f;  // log2(10000)/16
  if (bz < 2) {
    unsigned short* dst = (bz == 0) ? q_ws : k_ws;
#pragma unroll
    for (int mi = 0; mi < 2; ++mi)
#pragma unroll
      for (int r = 0; r < 4; ++r) {
        int row_g = m0 + w * 32 + mi * 16 + quad * 4 + r;
        int t_pos = row_g & 511;
        float v0 = acc[mi][0][r], v1 = acc[mi][1][r];
        {
          float i0 = (float)(ln >> 1);
          float f0 = exp2f(-i0 * R_LG);
          float f1 = exp2f(-(i0 + 8.0f) * R_LG);
          float s0, c0, s1, c1;
          sincosf((float)t_pos * f0, &s0, &c0);
          sincosf((float)t_pos * f1, &s1, &c1);
          float p0 = __shfl_xor(v0, 1), p1 = __shfl_xor(v1, 1);
          v0 = (ln & 1) ? (v0 * c0 + p0 * s0) : (v0 * c0 - p0 * s0);
          v1 = (ln & 1) ? (v1 * c1 + p1 * s1) : (v1 * c1 - p1 * s1);
        }
        dst[(size_t)row_g * 192 + ln] = f2bf(v0);
        dst[(size_t)row_g * 192 + 16 + ln] = f2bf(v1);
#pragma unroll
        for (int nj = 2; nj < 12; ++nj)
          dst[(size_t)row_g * 192 + nj * 16 + ln] = f2bf(acc[mi][nj][r]);
      }
  } else {
#pragma unroll
    for (int mi = 0; mi < 2; ++mi) {
      int rb = m0 + w * 32 + mi * 16 + quad * 4;  // 4 consecutive rows, one batch
      int bb = rb >> 9, t = rb & 511;
#pragma unroll
      for (int nj = 0; nj < 12; ++nj) {
        ushort4 pv;
        pv.x = f2bf(acc[mi][nj][0]);
        pv.y = f2bf(acc[mi][nj][1]);
        pv.z = f2bf(acc[mi][nj][2]);
        pv.w = f2bf(acc[mi][nj][3]);
        *(ushort4*)&v_ws[((size_t)bb * 192 + nj * 16 + ln) * 512 + t] = pv;
      }
    }
  }
}

// ---------------- kernel 3: causal flash attention (MFMA, KVBLK=32) -----------
// UNCHANGED from the passing round-7 version (2 blocks/CU; helped vs KVBLK=64).
__global__ __launch_bounds__(256) void attn_kernel(
    const unsigned short* __restrict__ q_ws, const unsigned short* __restrict__ k_ws,
    const unsigned short* __restrict__ v_ws, float* __restrict__ out) {
  __shared__ __align__(16) unsigned short K_lds[32 * 200];
  __shared__ __align__(16) unsigned short V_lds[192 * 40];   // V^T: [dim][key]
  __shared__ __align__(16) unsigned short P_lds[4][16 * 40]; // per-wave P
  const int tid = threadIdx.x;
  const int w = tid >> 6, l = tid & 63, quad = l >> 4, ln = l & 15;
  const int b = blockIdx.y;
  const int qt = (blockIdx.y < 32) ? blockIdx.x : 7 - blockIdx.x;
  const int q0 = qt * 64;

  // preload Q A-fragments
  short8 qf[6];
  {
    const unsigned short* qp =
        q_ws + (size_t)(b * 512 + q0 + w * 16 + ln) * 192 + quad * 8;
#pragma unroll
    for (int kk = 0; kk < 6; ++kk) qf[kk] = *(const short8*)(qp + kk * 32);
  }

  float m_i[4], l_i[4];
  floatx4 o[12];
#pragma unroll
  for (int r = 0; r < 4; ++r) { m_i[r] = -1e30f; l_i[r] = 0.f; }
#pragma unroll
  for (int nt = 0; nt < 12; ++nt) o[nt] = floatx4{0.f, 0.f, 0.f, 0.f};
  const float sm_scale = 0.07216878364870323f;  // 192^-0.5

  const int ktmax = 2 * qt + 1;
  for (int kt = 0; kt <= ktmax; ++kt) {
    const int k0 = kt * 32;
    __syncthreads();  // previous iteration's LDS reads done before overwrite
    // stage K tile [32][192]: 768 16B chunks
#pragma unroll
    for (int it = 0; it < 3; ++it) {
      int idx = it * 256 + tid;
      int row = idx / 24, c = idx - row * 24;
      uint4 v = *(const uint4*)(k_ws + (size_t)(b * 512 + k0 + row) * 192 + c * 8);
      *(uint4*)&K_lds[row * 200 + c * 8] = v;
    }
    // stage V^T tile [192][32]: 768 chunks
#pragma unroll
    for (int it = 0; it < 3; ++it) {
      int idx = it * 256 + tid;
      int row = idx >> 2, c = idx & 3;
      uint4 v = *(const uint4*)(v_ws + (size_t)(b * 192 + row) * 512 + k0 + c * 8);
      *(uint4*)&V_lds[row * 40 + c * 8] = v;
    }
    __syncthreads();

    // S = Q K^T (scaled)
    float s[2][4];
    __builtin_amdgcn_s_setprio(1);
#pragma unroll
    for (int nt = 0; nt < 2; ++nt) {
      floatx4 sa = floatx4{0.f, 0.f, 0.f, 0.f};
#pragma unroll
      for (int kk = 0; kk < 6; ++kk) {
        short8 kf = *(const short8*)&K_lds[(nt * 16 + ln) * 200 + kk * 32 + quad * 8];
        sa = __builtin_amdgcn_mfma_f32_16x16x32_bf16(qf[kk], kf, sa, 0, 0, 0);
      }
#pragma unroll
      for (int r = 0; r < 4; ++r) s[nt][r] = sa[r] * sm_scale;
    }
    __builtin_amdgcn_s_setprio(0);
    if (kt >= 2 * qt) {  // diagonal-region tiles
      int kd = (kt - 2 * qt) * 32;
#pragma unroll
      for (int nt = 0; nt < 2; ++nt)
#pragma unroll
        for (int r = 0; r < 4; ++r)
          if (kd + nt * 16 + ln > w * 16 + quad * 4 + r) s[nt][r] = -1e30f;
    }
    // online softmax (row = quad*4+r)
    float alpha[4];
#pragma unroll
    for (int r = 0; r < 4; ++r) {
      float mx = fmaxf(s[0][r], s[1][r]);
      mx = fmaxf(mx, __shfl_xor(mx, 1));
      mx = fmaxf(mx, __shfl_xor(mx, 2));
      mx = fmaxf(mx, __shfl_xor(mx, 4));
      mx = fmaxf(mx, __shfl_xor(mx, 8));
      float mnew = fmaxf(m_i[r], mx);
      alpha[r] = __expf(m_i[r] - mnew);
      float sum = 0.f;
#pragma unroll
      for (int nt = 0; nt < 2; ++nt) {
        s[nt][r] = __expf(s[nt][r] - mnew);
        sum += s[nt][r];
      }
      sum += __shfl_xor(sum, 1);
      sum += __shfl_xor(sum, 2);
      sum += __shfl_xor(sum, 4);
      sum += __shfl_xor(sum, 8);
      l_i[r] = l_i[r] * alpha[r] + sum;
      m_i[r] = mnew;
    }
#pragma unroll
    for (int nt = 0; nt < 12; ++nt)
#pragma unroll
      for (int r = 0; r < 4; ++r) o[nt][r] *= alpha[r];

    // P: C/D layout -> A layout via per-wave LDS
#pragma unroll
    for (int nt = 0; nt < 2; ++nt)
#pragma unroll
      for (int r = 0; r < 4; ++r)
        P_lds[w][(quad * 4 + r) * 40 + nt * 16 + ln] = f2bf(s[nt][r]);
    __asm__ volatile("s_waitcnt lgkmcnt(0)" ::: "memory");  // wave-local write->read

    // O += P V (single k-slab: KVBLK=32)
    __builtin_amdgcn_s_setprio(1);
    {
      short8 pf = *(const short8*)&P_lds[w][ln * 40 + quad * 8];
#pragma unroll
      for (int nt = 0; nt < 12; ++nt) {
        short8 vf = *(const short8*)&V_lds[(nt * 16 + ln) * 40 + quad * 8];
        o[nt] = __builtin_amdgcn_mfma_f32_16x16x32_bf16(pf, vf, o[nt], 0, 0, 0);
      }
    }
    __builtin_amdgcn_s_setprio(0);
  }

  // epilogue: O/l -> fp32 out [b][t][dim]
#pragma unroll
  for (int r = 0; r < 4; ++r) {
    float inv = 1.0f / l_i[r];
    size_t rowoff = (size_t)(b * 512 + q0 + w * 16 + quad * 4 + r) * 192;
#pragma unroll
    for (int nt = 0; nt < 12; ++nt)
      out[rowoff + nt * 16 + ln] = o[nt][r] * inv;
  }
}

extern "C" void kernel_launch(void* const* d_in, const int* in_sizes, int n_in,
                              void* d_out, int out_size, void* d_ws, size_t ws_size,
                              hipStream_t stream) {
  const float* x = (const float*)d_in[0];
  const float* Wq = (const float*)d_in[1];
  const float* Wk = (const float*)d_in[2];
  const float* Wv = (const float*)d_in[3];
  float* out = (float*)d_out;

  char* ws = (char*)d_ws;
  const size_t QKV_BYTES = (size_t)64 * 512 * 192 * 2;  // 12,582,912
  unsigned short* q_ws = (unsigned short*)(ws);
  unsigned short* k_ws = (unsigned short*)(ws + QKV_BYTES);
  unsigned short* v_ws = (unsigned short*)(ws + 2 * QKV_BYTES);
  unsigned short* Wt = (unsigned short*)(ws + 3 * QKV_BYTES);  // 884,736 B image

  hipLaunchKernelGGL(prep_w_kernel, dim3(216), dim3(256), 0, stream, Wq, Wk, Wv, Wt);
  hipLaunchKernelGGL(proj_kernel, dim3(256, 3), dim3(256), 0, stream, x, Wt, q_ws, k_ws, v_ws);
  hipLaunchKernelGGL(attn_kernel, dim3(8, 64), dim3(256), 0, stream, q_ws, k_ws, v_ws, out);
}